// Round 4
// baseline (3333.042 us; speedup 1.0000x reference)
//
#include <hip/hip_runtime.h>
#include <math.h>

#define THREADS 256

// Dims: B=8, C(seq)=10, F(dim)=48, H=W=64, HEADS=8, hd=6, MLP=192
// Stage2: NI=80 images, CH=96, PW=384, OUTF=48

// transposed shortcut weights [96][48], filled by kt_transpose each launch
__device__ float g_scwT[96 * 48];

// ---------------- Kernel T: transpose sc_w (48x96 -> 96x48), one-off ----------------
__global__ void kt_transpose(const float* __restrict__ sc_w) {
    int i = threadIdx.x + blockIdx.x * 256;
    if (i < 48 * 96) {
        int o = i / 96, k = i % 96;
        g_scwT[k * 48 + o] = sc_w[o * 96 + k];
    }
}

// ---------------- Kernel A: lane = token (unchanged from round 3) ----------------
#define LKS 49

__global__ __launch_bounds__(64, 3) void ka2_transformer(
    const float* __restrict__ x,
    const float* __restrict__ qkv_w, const float* __restrict__ qkv_b,
    const float* __restrict__ proj_w, const float* __restrict__ proj_b,
    const float* __restrict__ ff1_w, const float* __restrict__ ff1_b,
    const float* __restrict__ ff2_w, const float* __restrict__ ff2_b,
    float* __restrict__ t_out)
{
    __shared__ float tl[64 * LKS];     // per-lane token row (48 data + 1 pad)
    const int lane = threadIdx.x;

    // bijective XCD swizzle (grid not divisible by 8): chunked assignment
    const int nb  = gridDim.x;
    const int q8  = nb >> 3, r8 = nb & 7;
    const int xcd = blockIdx.x & 7, idx = blockIdx.x >> 3;
    const int wg  = (xcd < r8) ? xcd * (q8 + 1) + idx
                               : r8 * (q8 + 1) + (xcd - r8) * q8 + idx;

    const int s = lane / 10;
    const int c = lane - s * 10;                 // seq position 0..9
    const int g = wg * 6 + s;                    // global pixel (sequence) id
    const bool act = (lane < 60) && (g < 32768);
    const int b   = g >> 12;                     // batch image
    const int pix = g & 4095;

    float* tr = tl + lane * LKS;

    // ---- prologue: gather this token's 48 features ----
    if (act) {
        const float* xp = x + ((size_t)(b * 480 + c * 48)) * 4096 + pix;
        #pragma unroll
        for (int f = 0; f < 48; ++f) tr[f] = xp[(size_t)f * 4096];
    } else {
        #pragma unroll
        for (int f = 0; f < 48; ++f) tr[f] = 0.f;
    }

    const float scale = 0.4082482904638631f;     // 6^-0.5
    const float NEG = -3.4e38f;

    for (int l = 0; l < 2; ++l) {
        const float* qw  = qkv_w + l * 6912;
        const float* qb  = qkv_b + l * 144;
        const float* pw  = proj_w + l * 2304;
        const float* pb  = proj_b + l * 48;
        const float* f1w = ff1_w + l * 9216;
        const float* f1b = ff1_b + l * 192;
        const float* f2w = ff2_w + l * 9216;
        const float* f2b = ff2_b + l * 48;

        float pacc[48];
        #pragma unroll
        for (int o = 0; o < 48; ++o) pacc[o] = 0.f;

        for (int h = 0; h < 8; ++h) {
            float qa[6], ka[6], va[6];
            #pragma unroll
            for (int d = 0; d < 6; ++d) { qa[d] = 0.f; ka[d] = 0.f; va[d] = 0.f; }

            for (int k = 0; k < 48; ++k) {
                const float tk = tr[k];
                const float* wr = qw + k * 144 + h * 6;
                #pragma unroll
                for (int d = 0; d < 6; ++d) {
                    qa[d] += tk * wr[d];
                    ka[d] += tk * wr[48 + d];
                    va[d] += tk * wr[96 + d];
                }
            }
            #pragma unroll
            for (int d = 0; d < 6; ++d) {
                qa[d] += qb[h * 6 + d];
                ka[d] += qb[48 + h * 6 + d];
                va[d] += qb[96 + h * 6 + d];
            }

            float qm[6], qp[6], vm[6], vp[6];
            #pragma unroll
            for (int d = 0; d < 6; ++d) {
                qm[d] = __shfl_up(qa[d], 1);
                qp[d] = __shfl_down(qa[d], 1);
                vm[d] = __shfl_up(va[d], 1);
                vp[d] = __shfl_down(va[d], 1);
            }
            float s0 = 0.f, sm = 0.f, sp = 0.f;
            #pragma unroll
            for (int d = 0; d < 6; ++d) {
                s0 += ka[d] * qa[d];
                sm += ka[d] * qm[d];
                sp += ka[d] * qp[d];
            }
            s0 *= scale; sm *= scale; sp *= scale;
            if (c == 0) sm = NEG;
            if (c == 9) sp = NEG;
            const float mx = fmaxf(s0, fmaxf(sm, sp));
            const float em = expf(sm - mx), e0 = expf(s0 - mx), ep = expf(sp - mx);
            const float inv = 1.0f / (em + e0 + ep);

            #pragma unroll
            for (int d = 0; d < 6; ++d) {
                const float ov = (em * vm[d] + e0 * va[d] + ep * vp[d]) * inv;
                const float* wr = pw + (h * 6 + d) * 48;
                #pragma unroll
                for (int o = 0; o < 48; ++o) pacc[o] += ov * wr[o];
            }
        }
        #pragma unroll
        for (int f = 0; f < 48; ++f) tr[f] += pacc[f] + pb[f];

        float facc[48];
        #pragma unroll
        for (int o = 0; o < 48; ++o) facc[o] = 0.f;

        for (int cc = 0; cc < 8; ++cc) {
            float ha[24];
            #pragma unroll
            for (int j = 0; j < 24; ++j) ha[j] = 0.f;

            for (int k = 0; k < 48; ++k) {
                const float tk = tr[k];
                const float* wr = f1w + k * 192 + cc * 24;
                #pragma unroll
                for (int j = 0; j < 24; ++j) ha[j] += tk * wr[j];
            }
            #pragma unroll
            for (int j = 0; j < 24; ++j) {
                float v = ha[j] + f1b[cc * 24 + j];
                ha[j] = 0.5f * v * (1.f + erff(v * 0.70710678118654752f));
            }
            #pragma unroll
            for (int j = 0; j < 24; ++j) {
                const float hj = ha[j];
                const float* wr = f2w + (cc * 24 + j) * 48;
                #pragma unroll
                for (int o = 0; o < 48; ++o) facc[o] += hj * wr[o];
            }
        }
        #pragma unroll
        for (int f = 0; f < 48; ++f) tr[f] += facc[f] + f2b[f];
    }

    if (act) {
        float* dst = t_out + (size_t)g * 480 + c * 48;
        #pragma unroll
        for (int u = 0; u < 12; ++u) {
            float4 v;
            v.x = tr[u * 4]; v.y = tr[u * 4 + 1];
            v.z = tr[u * 4 + 2]; v.w = tr[u * 4 + 3];
            *(float4*)(dst + u * 4) = v;
        }
    }
}

// ---------------- Kernel B: depthwise 3x3 conv (SAME) + transpose to pixel-major ----------------
__global__ __launch_bounds__(THREADS) void kb_conv(
    const float* __restrict__ x, const float* __restrict__ t_in,
    const float* __restrict__ dw_w, const float* __restrict__ dw_b,
    float* __restrict__ z0)
{
    __shared__ float ct[100 * 97];     // 10x10 halo tile x 96 ch, stride 97 (bank pad)
    const int tid = threadIdx.x;
    const int blk = blockIdx.x;
    const int n = blk >> 6;            // image (b*10+c)
    const int tile = blk & 63;
    const int th0 = (tile >> 3) << 3;
    const int tw0 = (tile & 7) << 3;
    const int b = n / 10, c = n % 10;

    for (int idx = tid; idx < 4800; idx += THREADS) {
        int f = idx / 100, p = idx % 100;
        int py = p / 10, px = p % 10;
        int gh = th0 + py - 1, gw = tw0 + px - 1;
        float v = 0.f;
        if ((unsigned)gh < 64u && (unsigned)gw < 64u)
            v = x[((size_t)n * 48 + f) * 4096 + gh * 64 + gw];
        ct[p * 97 + f] = v;
    }
    for (int idx = tid; idx < 4800; idx += THREADS) {
        int p = idx / 48, f = idx % 48;
        int py = p / 10, px = p % 10;
        int gh = th0 + py - 1, gw = tw0 + px - 1;
        float v = 0.f;
        if ((unsigned)gh < 64u && (unsigned)gw < 64u)
            v = t_in[(size_t)(b * 4096 + gh * 64 + gw) * 480 + c * 48 + f];
        ct[p * 97 + 48 + f] = v;
    }
    __syncthreads();

    #pragma unroll 4
    for (int it = 0; it < 24; ++it) {
        int oidx = tid + it * THREADS;   // 24*256 == 6144 == 64px * 96ch
        int pxl = oidx / 96, ch = oidx % 96;
        int py = pxl >> 3, pxx = pxl & 7;
        const float* wp = dw_w + ch * 9;
        float acc = dw_b[ch];
        #pragma unroll
        for (int dy = 0; dy < 3; ++dy)
            #pragma unroll
            for (int dx = 0; dx < 3; ++dx)
                acc += ct[((py + dy) * 10 + pxx + dx) * 97 + ch] * wp[dy * 3 + dx];
        z0[((size_t)n * 4096 + (th0 + py) * 64 + (tw0 + pxx)) * 96 + ch] = acc;
    }
}

// ---------------- Kernel C (rewrite): lane = pixel ----------------
// One wave per block, 64 pixels. z-row per lane in LDS (stride 100, 16B aligned,
// even bank distribution for b128). Weights wave-uniform -> s_load. ha/facc in
// registers with static indexing only. No barriers in the compute loop.
// LDS 25.6KB -> 6 blocks/CU.
#define ZS 100

__global__ __launch_bounds__(64) void kc2_mlp(
    const float* __restrict__ x, const float* __restrict__ t_in,
    const float* __restrict__ z0,
    const float* __restrict__ ln_g, const float* __restrict__ ln_b,
    const float* __restrict__ pw1_w, const float* __restrict__ pw1_b,
    const float* __restrict__ pw2_w, const float* __restrict__ pw2_b,
    const float* __restrict__ sc_b,
    float* __restrict__ out)
{
    __shared__ float zb[64 * ZS];    // z rows; later reused for cat rows
    const int lane = threadIdx.x;
    const int blk = blockIdx.x;       // 5120
    const int n   = blk >> 6;         // image 0..79
    const int hw0 = (blk & 63) << 6;  // 64-pixel run
    const size_t pixbase = (size_t)n * 4096 + hw0;

    // ---- stage z0 cooperatively (contiguous 6144 floats) ----
    for (int idx = lane; idx < 1536; idx += 64) {
        float4 v = *(const float4*)(z0 + pixbase * 96 + (size_t)idx * 4);
        int p = idx / 24, c0 = (idx % 24) * 4;
        *(float4*)(&zb[p * ZS + c0]) = v;
    }
    __syncthreads();

    float* zr = zb + lane * ZS;

    // ---- LayerNorm in place, own row (FP order identical to previous kernel) ----
    {
        float mu = 0.f;
        for (int k = 0; k < 96; k += 4) {
            float4 v = *(const float4*)(zr + k);
            mu += v.x; mu += v.y; mu += v.z; mu += v.w;
        }
        mu *= (1.f / 96.f);
        float var = 0.f;
        for (int k = 0; k < 96; k += 4) {
            float4 v = *(const float4*)(zr + k);
            float d0 = v.x - mu, d1 = v.y - mu, d2 = v.z - mu, d3 = v.w - mu;
            var += d0 * d0; var += d1 * d1; var += d2 * d2; var += d3 * d3;
        }
        var *= (1.f / 96.f);
        float rs = rsqrtf(var + 1e-6f);
        for (int k = 0; k < 96; k += 4) {
            float4 v = *(const float4*)(zr + k);
            v.x = (v.x - mu) * rs * ln_g[k + 0] + ln_b[k + 0];
            v.y = (v.y - mu) * rs * ln_g[k + 1] + ln_b[k + 1];
            v.z = (v.z - mu) * rs * ln_g[k + 2] + ln_b[k + 2];
            v.w = (v.w - mu) * rs * ln_g[k + 3] + ln_b[k + 3];
            *(float4*)(zr + k) = v;
        }
    }
    // no barrier needed: every lane touches only its own row from here until cat staging

    float facc[48];
    #pragma unroll
    for (int o = 0; o < 48; ++o) facc[o] = pw2_b[o];

    // ---- pw1 + gelu + pw2, 16 chunks of 24 hidden units ----
    for (int jc = 0; jc < 16; ++jc) {
        const int j0 = jc * 24;
        float ha[24];
        #pragma unroll
        for (int j = 0; j < 24; ++j) ha[j] = 0.f;

        for (int k = 0; k < 96; k += 4) {
            float4 a = *(const float4*)(zr + k);
            #pragma unroll
            for (int kk = 0; kk < 4; ++kk) {
                const float e = (&a.x)[kk];
                const float* wr = pw1_w + (k + kk) * 384 + j0;   // wave-uniform -> s_load
                #pragma unroll
                for (int j = 0; j < 24; ++j) ha[j] += e * wr[j];
            }
        }
        #pragma unroll
        for (int j = 0; j < 24; ++j) {
            float v = ha[j] + pw1_b[j0 + j];
            ha[j] = 0.5f * v * (1.f + erff(v * 0.70710678118654752f));
        }
        #pragma unroll
        for (int j = 0; j < 24; ++j) {
            const float hj = ha[j];
            const float* wr = pw2_w + (j0 + j) * 48;             // wave-uniform -> s_load
            #pragma unroll
            for (int o = 0; o < 48; ++o) facc[o] += hj * wr[o];
        }
    }

    // ---- stage cat (x planar ch 0..47, t pixel-major ch 48..95) into zb ----
    __syncthreads();   // all lanes done reading z before overwrite
    for (int idx = lane; idx < 768; idx += 64) {
        int ch = idx >> 4, p0 = (idx & 15) << 2;
        float4 v = *(const float4*)(x + ((size_t)n * 48 + ch) * 4096 + hw0 + p0);
        zb[(p0 + 0) * ZS + ch] = v.x; zb[(p0 + 1) * ZS + ch] = v.y;
        zb[(p0 + 2) * ZS + ch] = v.z; zb[(p0 + 3) * ZS + ch] = v.w;
    }
    {
        const size_t tb = ((size_t)(n / 10) * 4096 + hw0);
        const int coff = (n % 10) * 48;
        for (int idx = lane; idx < 768; idx += 64) {
            int p = idx / 12, u0 = (idx % 12) * 4;
            float4 v = *(const float4*)(t_in + (tb + p) * 480 + coff + u0);
            *(float4*)(&zb[p * ZS + 48 + u0]) = v;
        }
    }
    __syncthreads();

    // ---- shortcut: facc += cat @ sc_w^T via transposed weights (k-contiguous) ----
    for (int k = 0; k < 96; k += 4) {
        float4 a = *(const float4*)(zr + k);
        #pragma unroll
        for (int kk = 0; kk < 4; ++kk) {
            const float e = (&a.x)[kk];
            const float* wr = g_scwT + (k + kk) * 48;            // wave-uniform -> s_load
            #pragma unroll
            for (int o = 0; o < 48; ++o) facc[o] += e * wr[o];
        }
    }

    // ---- store: planar, per-f coalesced (64 lanes = 256B contiguous) ----
    {
        float* op = out + (size_t)n * 48 * 4096 + hw0 + lane;
        #pragma unroll
        for (int f = 0; f < 48; ++f)
            op[(size_t)f * 4096] = facc[f] + sc_b[f];
    }
}

extern "C" void kernel_launch(void* const* d_in, const int* in_sizes, int n_in,
                              void* d_out, int out_size, void* d_ws, size_t ws_size,
                              hipStream_t stream) {
    const float* x      = (const float*)d_in[0];
    const float* qkv_w  = (const float*)d_in[1];
    const float* qkv_b  = (const float*)d_in[2];
    const float* proj_w = (const float*)d_in[3];
    const float* proj_b = (const float*)d_in[4];
    const float* ff1_w  = (const float*)d_in[5];
    const float* ff1_b  = (const float*)d_in[6];
    const float* ff2_w  = (const float*)d_in[7];
    const float* ff2_b  = (const float*)d_in[8];
    const float* dw_w   = (const float*)d_in[9];
    const float* dw_b   = (const float*)d_in[10];
    const float* ln_g   = (const float*)d_in[11];
    const float* ln_b   = (const float*)d_in[12];
    const float* pw1_w  = (const float*)d_in[13];
    const float* pw1_b  = (const float*)d_in[14];
    const float* pw2_w  = (const float*)d_in[15];
    const float* pw2_b  = (const float*)d_in[16];
    const float* sc_w   = (const float*)d_in[17];
    const float* sc_b   = (const float*)d_in[18];
    float* out = (float*)d_out;

    // workspace: t_final (B*H*W,10,48) = 15,728,640 f ; z0 (80*4096,96) = 31,457,280 f
    float* t_out = (float*)d_ws;
    float* z0    = t_out + 15728640ull;

    kt_transpose<<<18, 256, 0, stream>>>(sc_w);
    ka2_transformer<<<5462, 64, 0, stream>>>(x, qkv_w, qkv_b, proj_w, proj_b,
                                             ff1_w, ff1_b, ff2_w, ff2_b, t_out);
    kb_conv<<<5120, THREADS, 0, stream>>>(x, t_out, dw_w, dw_b, z0);
    kc2_mlp<<<5120, 64, 0, stream>>>(x, t_out, z0, ln_g, ln_b,
                                     pw1_w, pw1_b, pw2_w, pw2_b, sc_b, out);
}

// Round 5
// 2622.753 us; speedup vs baseline: 1.2708x; 1.2708x over previous
//
#include <hip/hip_runtime.h>
#include <math.h>

#define THREADS 256

// Dims: B=8, C(seq)=10, F(dim)=48, H=W=64, HEADS=8, hd=6, MLP=192
// Stage2: NI=80 images, CH=96, PW=384, OUTF=48

// transposed shortcut weights [96][48], filled by kt_transpose each launch
__device__ float g_scwT[96 * 48];

// ---------------- Kernel T: transpose sc_w (48x96 -> 96x48), one-off ----------------
__global__ void kt_transpose(const float* __restrict__ sc_w) {
    int i = threadIdx.x + blockIdx.x * 256;
    if (i < 48 * 96) {
        int o = i / 96, k = i % 96;
        g_scwT[k * 48 + o] = sc_w[o * 96 + k];
    }
}

// ---------------- Kernel A: lane = token (unchanged) ----------------
#define LKS 49

__global__ __launch_bounds__(64, 3) void ka2_transformer(
    const float* __restrict__ x,
    const float* __restrict__ qkv_w, const float* __restrict__ qkv_b,
    const float* __restrict__ proj_w, const float* __restrict__ proj_b,
    const float* __restrict__ ff1_w, const float* __restrict__ ff1_b,
    const float* __restrict__ ff2_w, const float* __restrict__ ff2_b,
    float* __restrict__ t_out)
{
    __shared__ float tl[64 * LKS];     // per-lane token row (48 data + 1 pad)
    const int lane = threadIdx.x;

    // bijective XCD swizzle (grid not divisible by 8): chunked assignment
    const int nb  = gridDim.x;
    const int q8  = nb >> 3, r8 = nb & 7;
    const int xcd = blockIdx.x & 7, idx = blockIdx.x >> 3;
    const int wg  = (xcd < r8) ? xcd * (q8 + 1) + idx
                               : r8 * (q8 + 1) + (xcd - r8) * q8 + idx;

    const int s = lane / 10;
    const int c = lane - s * 10;                 // seq position 0..9
    const int g = wg * 6 + s;                    // global pixel (sequence) id
    const bool act = (lane < 60) && (g < 32768);
    const int b   = g >> 12;                     // batch image
    const int pix = g & 4095;

    float* tr = tl + lane * LKS;

    if (act) {
        const float* xp = x + ((size_t)(b * 480 + c * 48)) * 4096 + pix;
        #pragma unroll
        for (int f = 0; f < 48; ++f) tr[f] = xp[(size_t)f * 4096];
    } else {
        #pragma unroll
        for (int f = 0; f < 48; ++f) tr[f] = 0.f;
    }

    const float scale = 0.4082482904638631f;     // 6^-0.5
    const float NEG = -3.4e38f;

    for (int l = 0; l < 2; ++l) {
        const float* qw  = qkv_w + l * 6912;
        const float* qb  = qkv_b + l * 144;
        const float* pw  = proj_w + l * 2304;
        const float* pb  = proj_b + l * 48;
        const float* f1w = ff1_w + l * 9216;
        const float* f1b = ff1_b + l * 192;
        const float* f2w = ff2_w + l * 9216;
        const float* f2b = ff2_b + l * 48;

        float pacc[48];
        #pragma unroll
        for (int o = 0; o < 48; ++o) pacc[o] = 0.f;

        for (int h = 0; h < 8; ++h) {
            float qa[6], ka[6], va[6];
            #pragma unroll
            for (int d = 0; d < 6; ++d) { qa[d] = 0.f; ka[d] = 0.f; va[d] = 0.f; }

            for (int k = 0; k < 48; ++k) {
                const float tk = tr[k];
                const float* wr = qw + k * 144 + h * 6;
                #pragma unroll
                for (int d = 0; d < 6; ++d) {
                    qa[d] += tk * wr[d];
                    ka[d] += tk * wr[48 + d];
                    va[d] += tk * wr[96 + d];
                }
            }
            #pragma unroll
            for (int d = 0; d < 6; ++d) {
                qa[d] += qb[h * 6 + d];
                ka[d] += qb[48 + h * 6 + d];
                va[d] += qb[96 + h * 6 + d];
            }

            float qm[6], qp[6], vm[6], vp[6];
            #pragma unroll
            for (int d = 0; d < 6; ++d) {
                qm[d] = __shfl_up(qa[d], 1);
                qp[d] = __shfl_down(qa[d], 1);
                vm[d] = __shfl_up(va[d], 1);
                vp[d] = __shfl_down(va[d], 1);
            }
            float s0 = 0.f, sm = 0.f, sp = 0.f;
            #pragma unroll
            for (int d = 0; d < 6; ++d) {
                s0 += ka[d] * qa[d];
                sm += ka[d] * qm[d];
                sp += ka[d] * qp[d];
            }
            s0 *= scale; sm *= scale; sp *= scale;
            if (c == 0) sm = NEG;
            if (c == 9) sp = NEG;
            const float mx = fmaxf(s0, fmaxf(sm, sp));
            const float em = expf(sm - mx), e0 = expf(s0 - mx), ep = expf(sp - mx);
            const float inv = 1.0f / (em + e0 + ep);

            #pragma unroll
            for (int d = 0; d < 6; ++d) {
                const float ov = (em * vm[d] + e0 * va[d] + ep * vp[d]) * inv;
                const float* wr = pw + (h * 6 + d) * 48;
                #pragma unroll
                for (int o = 0; o < 48; ++o) pacc[o] += ov * wr[o];
            }
        }
        #pragma unroll
        for (int f = 0; f < 48; ++f) tr[f] += pacc[f] + pb[f];

        float facc[48];
        #pragma unroll
        for (int o = 0; o < 48; ++o) facc[o] = 0.f;

        for (int cc = 0; cc < 8; ++cc) {
            float ha[24];
            #pragma unroll
            for (int j = 0; j < 24; ++j) ha[j] = 0.f;

            for (int k = 0; k < 48; ++k) {
                const float tk = tr[k];
                const float* wr = f1w + k * 192 + cc * 24;
                #pragma unroll
                for (int j = 0; j < 24; ++j) ha[j] += tk * wr[j];
            }
            #pragma unroll
            for (int j = 0; j < 24; ++j) {
                float v = ha[j] + f1b[cc * 24 + j];
                ha[j] = 0.5f * v * (1.f + erff(v * 0.70710678118654752f));
            }
            #pragma unroll
            for (int j = 0; j < 24; ++j) {
                const float hj = ha[j];
                const float* wr = f2w + (cc * 24 + j) * 48;
                #pragma unroll
                for (int o = 0; o < 48; ++o) facc[o] += hj * wr[o];
            }
        }
        #pragma unroll
        for (int f = 0; f < 48; ++f) tr[f] += facc[f] + f2b[f];
    }

    if (act) {
        float* dst = t_out + (size_t)g * 480 + c * 48;
        #pragma unroll
        for (int u = 0; u < 12; ++u) {
            float4 v;
            v.x = tr[u * 4]; v.y = tr[u * 4 + 1];
            v.z = tr[u * 4 + 2]; v.w = tr[u * 4 + 3];
            *(float4*)(dst + u * 4) = v;
        }
    }
}

// ---------------- Kernel B: depthwise 3x3 conv (SAME) + transpose to pixel-major ----------------
__global__ __launch_bounds__(THREADS) void kb_conv(
    const float* __restrict__ x, const float* __restrict__ t_in,
    const float* __restrict__ dw_w, const float* __restrict__ dw_b,
    float* __restrict__ z0)
{
    __shared__ float ct[100 * 97];     // 10x10 halo tile x 96 ch, stride 97 (bank pad)
    const int tid = threadIdx.x;
    const int blk = blockIdx.x;
    const int n = blk >> 6;            // image (b*10+c)
    const int tile = blk & 63;
    const int th0 = (tile >> 3) << 3;
    const int tw0 = (tile & 7) << 3;
    const int b = n / 10, c = n % 10;

    for (int idx = tid; idx < 4800; idx += THREADS) {
        int f = idx / 100, p = idx % 100;
        int py = p / 10, px = p % 10;
        int gh = th0 + py - 1, gw = tw0 + px - 1;
        float v = 0.f;
        if ((unsigned)gh < 64u && (unsigned)gw < 64u)
            v = x[((size_t)n * 48 + f) * 4096 + gh * 64 + gw];
        ct[p * 97 + f] = v;
    }
    for (int idx = tid; idx < 4800; idx += THREADS) {
        int p = idx / 48, f = idx % 48;
        int py = p / 10, px = p % 10;
        int gh = th0 + py - 1, gw = tw0 + px - 1;
        float v = 0.f;
        if ((unsigned)gh < 64u && (unsigned)gw < 64u)
            v = t_in[(size_t)(b * 4096 + gh * 64 + gw) * 480 + c * 48 + f];
        ct[p * 97 + 48 + f] = v;
    }
    __syncthreads();

    #pragma unroll 4
    for (int it = 0; it < 24; ++it) {
        int oidx = tid + it * THREADS;   // 24*256 == 6144 == 64px * 96ch
        int pxl = oidx / 96, ch = oidx % 96;
        int py = pxl >> 3, pxx = pxl & 7;
        const float* wp = dw_w + ch * 9;
        float acc = dw_b[ch];
        #pragma unroll
        for (int dy = 0; dy < 3; ++dy)
            #pragma unroll
            for (int dx = 0; dx < 3; ++dx)
                acc += ct[((py + dy) * 10 + pxx + dx) * 97 + ch] * wp[dy * 3 + dx];
        z0[((size_t)n * 4096 + (th0 + py) * 64 + (tw0 + pxx)) * 96 + ch] = acc;
    }
}

// ---------------- Kernel C (v3): lane = pixel, ZERO LDS ----------------
// Each lane owns one pixel. Its z row (96 floats, pixel-major in z0) is read
// directly from global: the block's 24.6KB slice is L1-resident after pass 1
// (18 passes total). LN stats in registers; LN affine recomputed per read
// (identical values -> identical numerics). Weights wave-uniform -> s_load.
// ha/facc in registers, static indexing only. No LDS, no barriers ->
// 16 waves/CU at VGPR<=128 (launch_bounds(64,4)).
__global__ __launch_bounds__(64, 4) void kc3_mlp(
    const float* __restrict__ x, const float* __restrict__ t_in,
    const float* __restrict__ z0,
    const float* __restrict__ ln_g, const float* __restrict__ ln_b,
    const float* __restrict__ pw1_w, const float* __restrict__ pw1_b,
    const float* __restrict__ pw2_w, const float* __restrict__ pw2_b,
    const float* __restrict__ sc_b,
    float* __restrict__ out)
{
    const int lane = threadIdx.x;
    const int blk = blockIdx.x;       // 5120
    const int n   = blk >> 6;         // image 0..79
    const int hw0 = (blk & 63) << 6;  // 64-pixel run
    const float* zr = z0 + ((size_t)n * 4096 + hw0 + lane) * 96;

    // ---- LN stats (mu, rs) — FP order matches prior kernel ----
    float mu = 0.f;
    for (int k = 0; k < 96; k += 4) {
        float4 v = *(const float4*)(zr + k);
        mu += v.x; mu += v.y; mu += v.z; mu += v.w;
    }
    mu *= (1.f / 96.f);
    float var = 0.f;
    for (int k = 0; k < 96; k += 4) {
        float4 v = *(const float4*)(zr + k);
        float d0 = v.x - mu, d1 = v.y - mu, d2 = v.z - mu, d3 = v.w - mu;
        var += d0 * d0; var += d1 * d1; var += d2 * d2; var += d3 * d3;
    }
    var *= (1.f / 96.f);
    const float rs = rsqrtf(var + 1e-6f);

    float facc[48];
    #pragma unroll
    for (int o = 0; o < 48; ++o) facc[o] = pw2_b[o];

    // ---- pw1 + gelu + pw2, 16 chunks of 24 hidden units ----
    for (int jc = 0; jc < 16; ++jc) {
        const int j0 = jc * 24;
        float ha[24];
        #pragma unroll
        for (int j = 0; j < 24; ++j) ha[j] = 0.f;

        for (int k = 0; k < 96; k += 4) {
            float4 v = *(const float4*)(zr + k);
            #pragma unroll
            for (int kk = 0; kk < 4; ++kk) {
                const float e = ((&v.x)[kk] - mu) * rs * ln_g[k + kk] + ln_b[k + kk];
                const float* wr = pw1_w + (k + kk) * 384 + j0;   // wave-uniform -> s_load
                #pragma unroll
                for (int j = 0; j < 24; ++j) ha[j] += e * wr[j];
            }
        }
        #pragma unroll
        for (int j = 0; j < 24; ++j) {
            float v = ha[j] + pw1_b[j0 + j];
            ha[j] = 0.5f * v * (1.f + erff(v * 0.70710678118654752f));
        }
        #pragma unroll
        for (int j = 0; j < 24; ++j) {
            const float hj = ha[j];
            const float* wr = pw2_w + (j0 + j) * 48;             // wave-uniform -> s_load
            #pragma unroll
            for (int o = 0; o < 48; ++o) facc[o] += hj * wr[o];
        }
    }

    // ---- shortcut: facc += cat @ sc_w^T, k ascending (x part 0..47, t part 48..95) ----
    {
        const float* xp = x + ((size_t)n * 48) * 4096 + hw0 + lane;
        for (int k = 0; k < 48; k += 4) {
            const float e0 = xp[(size_t)(k + 0) * 4096];
            const float e1 = xp[(size_t)(k + 1) * 4096];
            const float e2 = xp[(size_t)(k + 2) * 4096];
            const float e3 = xp[(size_t)(k + 3) * 4096];
            const float* w0 = g_scwT + (k + 0) * 48;
            const float* w1 = g_scwT + (k + 1) * 48;
            const float* w2 = g_scwT + (k + 2) * 48;
            const float* w3 = g_scwT + (k + 3) * 48;
            #pragma unroll
            for (int o = 0; o < 48; ++o) facc[o] += e0 * w0[o];
            #pragma unroll
            for (int o = 0; o < 48; ++o) facc[o] += e1 * w1[o];
            #pragma unroll
            for (int o = 0; o < 48; ++o) facc[o] += e2 * w2[o];
            #pragma unroll
            for (int o = 0; o < 48; ++o) facc[o] += e3 * w3[o];
        }
        const float* tp = t_in + ((size_t)((n / 10) * 4096 + hw0 + lane)) * 480 + (n % 10) * 48;
        for (int u = 0; u < 12; ++u) {
            float4 v = *(const float4*)(tp + u * 4);
            #pragma unroll
            for (int kk = 0; kk < 4; ++kk) {
                const float e = (&v.x)[kk];
                const float* wr = g_scwT + (48 + u * 4 + kk) * 48;
                #pragma unroll
                for (int o = 0; o < 48; ++o) facc[o] += e * wr[o];
            }
        }
    }

    // ---- store: planar, per-f coalesced (64 lanes = 256B contiguous) ----
    {
        float* op = out + (size_t)n * 48 * 4096 + hw0 + lane;
        #pragma unroll
        for (int f = 0; f < 48; ++f)
            op[(size_t)f * 4096] = facc[f] + sc_b[f];
    }
}

extern "C" void kernel_launch(void* const* d_in, const int* in_sizes, int n_in,
                              void* d_out, int out_size, void* d_ws, size_t ws_size,
                              hipStream_t stream) {
    const float* x      = (const float*)d_in[0];
    const float* qkv_w  = (const float*)d_in[1];
    const float* qkv_b  = (const float*)d_in[2];
    const float* proj_w = (const float*)d_in[3];
    const float* proj_b = (const float*)d_in[4];
    const float* ff1_w  = (const float*)d_in[5];
    const float* ff1_b  = (const float*)d_in[6];
    const float* ff2_w  = (const float*)d_in[7];
    const float* ff2_b  = (const float*)d_in[8];
    const float* dw_w   = (const float*)d_in[9];
    const float* dw_b   = (const float*)d_in[10];
    const float* ln_g   = (const float*)d_in[11];
    const float* ln_b   = (const float*)d_in[12];
    const float* pw1_w  = (const float*)d_in[13];
    const float* pw1_b  = (const float*)d_in[14];
    const float* pw2_w  = (const float*)d_in[15];
    const float* pw2_b  = (const float*)d_in[16];
    const float* sc_w   = (const float*)d_in[17];
    const float* sc_b   = (const float*)d_in[18];
    float* out = (float*)d_out;

    // workspace: t_final (B*H*W,10,48) = 15,728,640 f ; z0 (80*4096,96) = 31,457,280 f
    float* t_out = (float*)d_ws;
    float* z0    = t_out + 15728640ull;

    kt_transpose<<<18, 256, 0, stream>>>(sc_w);
    ka2_transformer<<<5462, 64, 0, stream>>>(x, qkv_w, qkv_b, proj_w, proj_b,
                                             ff1_w, ff1_b, ff2_w, ff2_b, t_out);
    kb_conv<<<5120, THREADS, 0, stream>>>(x, t_out, dw_w, dw_b, z0);
    kc3_mlp<<<5120, 64, 0, stream>>>(x, t_out, z0, ln_g, ln_b,
                                     pw1_w, pw1_b, pw2_w, pw2_b, sc_b, out);
}